// Round 4
// baseline (523.958 us; speedup 1.0000x reference)
//
#include <hip/hip_runtime.h>
#include <math.h>

#define IN_C   128
#define OUT_C  64
#define EDIM   16
#define EHID   32
#define GN_EPS 1e-5f

typedef unsigned long long u64;

__device__ __forceinline__ float dot4(float4 a, float4 b) {
    return a.x * b.x + a.y * b.y + a.z * b.z + a.w * b.w;
}
__device__ __forceinline__ void fma4(float4& a, float s, float4 w) {
    a.x = fmaf(s, w.x, a.x); a.y = fmaf(s, w.y, a.y);
    a.z = fmaf(s, w.z, a.z); a.w = fmaf(s, w.w, a.w);
}
__device__ __forceinline__ float getc(float4 v, int j) {
    return j == 0 ? v.x : j == 1 ? v.y : j == 2 ? v.z : v.w;
}

// ---------------------------------------------------------------------------
// K0: init  degcnt = {cnt:0, deg:1.0 fixed-point} (self-loop), sums = 0
// ---------------------------------------------------------------------------
__global__ void k_init(u64* __restrict__ degcnt, float* __restrict__ sums, int N) {
    int i = blockIdx.x * 256 + threadIdx.x;
    if (i < N) degcnt[i] = (1ull << 32);          // deg = 1.0 in 2^32 fixed point
    if (i < 2 * OUT_C) sums[i] = 0.f;
}

// ---------------------------------------------------------------------------
// K1: fused edge phase, SPLIT-K MLP. k_edge was LDS-issue-bound (128
// ds_read_b128/wave ≈ 62us of CU LDS pipe; VALUBusy only 28%). Lane pair
// (2k,2k+1) splits the 32 hidden units: even lane units 0-15, odd lane
// 16-31, each for BOTH edges of the pair -> 64 LDS instr/wave (halved).
// Partials combine via 2x shfl_xor(1); each lane finalizes its OWN edge.
// ATOMIC SCHEME UNCHANGED (R0-proven): ONE u64 RMW-with-return per thread,
// issued AFTER the MLP. R1 (early issue) and R2 (4 atomics/thread) both
// triggered a ~20x cross-XCD coherence storm — do not deviate.
// No early return before the shuffles (full wave must participate).
// tmp[e] = {row | rank<<17, ew}
// ---------------------------------------------------------------------------
__global__ __launch_bounds__(256, 8)
void k_edge(const float* __restrict__ ea, const int* __restrict__ ei,
            const float* __restrict__ w1, const float* __restrict__ b1,
            const float* __restrict__ w2, const float* __restrict__ b2,
            u64* __restrict__ degcnt, int2* __restrict__ tmp, int E) {
    __shared__ float4 sw1[EHID][4];
    __shared__ float  sb1[EHID];
    __shared__ float  sw2[EHID];
    __shared__ float  sb2;
    int tid = threadIdx.x;
    if (tid < 128) {
        const float4* w1v = (const float4*)w1;
        sw1[tid >> 2][tid & 3] = w1v[tid];
    }
    if (tid < EHID) { sb1[tid] = b1[tid]; sw2[tid] = w2[tid]; }
    if (tid == 0)   sb2 = b2[0];
    __syncthreads();

    int e  = blockIdx.x * 256 + tid;     // own edge
    int eb = e & ~1;                     // pair base
    int e0c = min(eb,     E - 1);
    int e1c = min(eb + 1, E - 1);
    int half = tid & 1;                  // 0: hidden units 0-15, 1: 16-31

    const float4* p0 = (const float4*)ea + (size_t)e0c * 4;
    const float4* p1 = (const float4*)ea + (size_t)e1c * 4;
    float4 A0 = p0[0], A1 = p0[1], A2 = p0[2], A3 = p0[3];
    float4 B0 = p1[0], B1 = p1[1], B2 = p1[2], B3 = p1[3];

    float zp0 = 0.f, zp1 = 0.f;          // partial z for edge eb+0 / eb+1
    int jbase = half << 4;
    #pragma unroll
    for (int j = 0; j < 16; ++j) {
        int jj = jbase + j;
        float4 w0 = sw1[jj][0], w1v = sw1[jj][1], w2v = sw1[jj][2], w3v = sw1[jj][3];
        float bj = sb1[jj], wj = sw2[jj];
        float h0 = dot4(A0, w0) + dot4(A1, w1v) + dot4(A2, w2v) + dot4(A3, w3v) + bj;
        float h1 = dot4(B0, w0) + dot4(B1, w1v) + dot4(B2, w2v) + dot4(B3, w3v) + bj;
        zp0 += fmaxf(h0, 0.f) * wj;
        zp1 += fmaxf(h1, 0.f) * wj;
    }
    float o0 = __shfl_xor(zp0, 1, 64);
    float o1 = __shfl_xor(zp1, 1, 64);
    float z = sb2 + (half ? (zp1 + o1) : (zp0 + o0));

    if (e < E) {
        float ewv = 1.f / (1.f + __expf(-z));
        int row = ei[e];
        int col = ei[E + e];
        u64 inc = (1ull << 44) | (u64)(ewv * 4294967296.0f);   // {cnt+=1, deg+=ew}
        u64 old = atomicAdd(&degcnt[col], inc);
        int rank = (int)(old >> 44);                            // edges before this one
        tmp[e] = make_int2(row | (rank << 17), __float_as_int(ewv));
    }
}

// ---------------------------------------------------------------------------
// K2 (fallback path only): unpack degcnt -> dinv and cnt
// ---------------------------------------------------------------------------
__global__ void k_finish(const u64* __restrict__ degcnt, float* __restrict__ dinv,
                         int* __restrict__ cnt, int N) {
    int i = blockIdx.x * 256 + threadIdx.x;
    if (i < N) {
        u64 v = degcnt[i];
        float deg = (float)(v & ((1ull << 44) - 1)) * (1.f / 4294967296.f);
        dinv[i] = rsqrtf(deg);                    // deg >= 1 always
        cnt[i] = (int)(v >> 44);
    }
}

// ---------------------------------------------------------------------------
// scan1 (CSR path): fused k_finish + block-local exclusive scan of cnt.
// full_start(i) = start[i] + bsums[i>>8]  (scan3 fused into consumers)
// ---------------------------------------------------------------------------
__global__ void k_scan1(const u64* __restrict__ degcnt, int* __restrict__ start,
                        int* __restrict__ bsums, float* __restrict__ dinv,
                        int* __restrict__ cnt, int N) {
    __shared__ int s[256];
    int t = threadIdx.x;
    int i = blockIdx.x * 256 + t;
    int v = 0;
    if (i < N) {
        u64 dv = degcnt[i];
        v = (int)(dv >> 44);
        float deg = (float)(dv & ((1ull << 44) - 1)) * (1.f / 4294967296.f);
        dinv[i] = rsqrtf(deg);
        cnt[i] = v;
    }
    s[t] = v;
    __syncthreads();
    #pragma unroll
    for (int off = 1; off < 256; off <<= 1) {
        int u = (t >= off) ? s[t - off] : 0;
        __syncthreads();
        s[t] += u;
        __syncthreads();
    }
    if (i < N) start[i] = s[t] - v;
    if (t == 255) bsums[blockIdx.x] = s[255];
}
__global__ void k_scan2(int* __restrict__ bsums, int nb) {
    __shared__ int s[1024];
    int t = threadIdx.x;
    s[t] = (t < nb) ? bsums[t] : 0;
    __syncthreads();
    #pragma unroll
    for (int off = 1; off < 1024; off <<= 1) {
        int u = (t >= off) ? s[t - off] : 0;
        __syncthreads();
        s[t] += u;
        __syncthreads();
    }
    if (t < nb) bsums[t] = (t == 0) ? 0 : s[t - 1];
}

// ---------------------------------------------------------------------------
// pass2: atomic-free permute — rec[full_start[col]+rank] = {row, ew}
// ---------------------------------------------------------------------------
__global__ void k_pass2(const int* __restrict__ ei, const int2* __restrict__ tmp,
                        const int* __restrict__ start, const int* __restrict__ bsums,
                        int2* __restrict__ rec, int E) {
    int e = blockIdx.x * 256 + threadIdx.x;
    if (e >= E) return;
    int col = ei[E + e];
    int2 t = tmp[e];
    int rank = ((unsigned)t.x) >> 17;
    int pos = start[col] + bsums[col >> 8] + rank;
    rec[pos] = make_int2(t.x & 0x1FFFF, t.y);
}

// ---------------------------------------------------------------------------
// K3: xts = dinv * (x @ lin_w^T)  — register-tiled 4 rows x 4 ch/lane
// ---------------------------------------------------------------------------
__global__ void k_xt(const float* __restrict__ x, const float* __restrict__ lw,
                     const float* __restrict__ dinv, float* __restrict__ xts, int N) {
    __shared__ float swt[IN_C * OUT_C];
    int tid = threadIdx.x;
    for (int i = tid; i < IN_C * OUT_C; i += 256) {
        int k = i >> 6, c = i & 63;
        swt[i] = lw[c * IN_C + k];
    }
    __syncthreads();

    int lane = tid & 63;
    int c4 = lane & 15;
    int rq = lane >> 4;
    int rbase = blockIdx.x * 64 + (tid >> 6) * 16 + rq * 4;

    int r0 = min(rbase + 0, N - 1), r1 = min(rbase + 1, N - 1);
    int r2 = min(rbase + 2, N - 1), r3 = min(rbase + 3, N - 1);
    const float4* x4 = (const float4*)x;
    float4 acc0 = {0,0,0,0}, acc1 = {0,0,0,0}, acc2 = {0,0,0,0}, acc3 = {0,0,0,0};

    #pragma unroll 4
    for (int k4 = 0; k4 < IN_C / 4; ++k4) {
        float4 xv0 = x4[(size_t)r0 * 32 + k4];
        float4 xv1 = x4[(size_t)r1 * 32 + k4];
        float4 xv2 = x4[(size_t)r2 * 32 + k4];
        float4 xv3 = x4[(size_t)r3 * 32 + k4];
        #pragma unroll
        for (int j = 0; j < 4; ++j) {
            float4 wv = *(const float4*)&swt[(k4 * 4 + j) * OUT_C + (c4 << 2)];
            fma4(acc0, getc(xv0, j), wv);
            fma4(acc1, getc(xv1, j), wv);
            fma4(acc2, getc(xv2, j), wv);
            fma4(acc3, getc(xv3, j), wv);
        }
    }
    int cc = c4 << 2;
    #pragma unroll
    for (int i = 0; i < 4; ++i) {
        int r = rbase + i;
        if (r < N) {
            float d = dinv[r];
            float4 a = i == 0 ? acc0 : i == 1 ? acc1 : i == 2 ? acc2 : acc3;
            a.x *= d; a.y *= d; a.z *= d; a.w *= d;
            *(float4*)&xts[(size_t)r * OUT_C + cc] = a;
        }
    }
}

// ---------------------------------------------------------------------------
// gather: one wave per node, lane = channel; unroll-8.
// out = bias + dinv[node] * (sum_j ew_j * xts[row_j] + xts[node])
// ---------------------------------------------------------------------------
__global__ void k_gather(const int2* __restrict__ rec, const int* __restrict__ start,
                         const int* __restrict__ bsums, const int* __restrict__ cnt,
                         const float* __restrict__ dinv, const float* __restrict__ xts,
                         const float* __restrict__ bias, float* __restrict__ out, int N) {
    int node = blockIdx.x * 4 + (threadIdx.x >> 6);
    if (node >= N) return;
    int lane = threadIdx.x & 63;
    int beg = start[node] + bsums[node >> 8];
    int num = cnt[node];
    float acc = xts[((size_t)node << 6) + lane];      // self-loop term
    int j = 0;
    for (; j + 8 <= num; j += 8) {
        int2 rc[8];
        #pragma unroll
        for (int u = 0; u < 8; ++u) rc[u] = rec[beg + j + u];
        float v[8];
        #pragma unroll
        for (int u = 0; u < 8; ++u) v[u] = xts[((size_t)rc[u].x << 6) + lane];
        #pragma unroll
        for (int u = 0; u < 8; ++u) acc = fmaf(__int_as_float(rc[u].y), v[u], acc);
    }
    for (; j < num; ++j) {
        int2 rc = rec[beg + j];
        acc = fmaf(__int_as_float(rc.y), xts[((size_t)rc.x << 6) + lane], acc);
    }
    out[((size_t)node << 6) + lane] = bias[lane] + dinv[node] * acc;
}

// ---------------------------------------------------------------------------
// fallback (emergency, if ws too small for rec): atomic scatter path
// ---------------------------------------------------------------------------
__global__ void k_init_out(const float* __restrict__ bias, const float* __restrict__ dinv,
                           const float* __restrict__ xts, float* __restrict__ out, int total) {
    int t = blockIdx.x * 256 + threadIdx.x;
    if (t >= total) return;
    int i = t >> 6, c = t & 63;
    out[t] = bias[c] + dinv[i] * xts[t];
}
__global__ void k_scatter(const int* __restrict__ ei, const int2* __restrict__ tmp,
                          const float* __restrict__ dinv, const float* __restrict__ xts,
                          float* __restrict__ out, int E) {
    int t = blockIdx.x * 256 + threadIdx.x;
    int e = t >> 6;
    if (e >= E) return;
    int lane = t & 63;
    int2 tm = tmp[e];
    int row = tm.x & 0x1FFFF;
    int col = ei[E + e];
    float w = dinv[col] * __int_as_float(tm.y);
    atomicAdd(out + (size_t)col * OUT_C + lane, w * xts[(size_t)row * OUT_C + lane]);
}

// ---------------------------------------------------------------------------
// PReLU + GraphNorm stats + apply
// ---------------------------------------------------------------------------
__global__ void k_stats(const float* __restrict__ out, const float* __restrict__ pa,
                        float* __restrict__ sums, int total) {
    __shared__ float r1[256], r2[256];
    float a = pa[0];
    float s = 0.f, s2 = 0.f;
    int stride = gridDim.x * 256;
    for (int t = blockIdx.x * 256 + threadIdx.x; t < total; t += stride) {
        float v = out[t];
        float y = v >= 0.f ? v : a * v;
        s += y; s2 += y * y;
    }
    int tid = threadIdx.x;
    r1[tid] = s; r2[tid] = s2;
    __syncthreads();
    if (tid < 64) {
        float t1 = r1[tid] + r1[tid + 64] + r1[tid + 128] + r1[tid + 192];
        float t2 = r2[tid] + r2[tid + 64] + r2[tid + 128] + r2[tid + 192];
        atomicAdd(&sums[tid], t1);
        atomicAdd(&sums[OUT_C + tid], t2);
    }
}
__global__ void k_apply(float* __restrict__ out, const float* __restrict__ pa,
                        const float* __restrict__ sums,
                        const float* __restrict__ gw, const float* __restrict__ gb,
                        const float* __restrict__ gms, int total, float invN) {
    int t = blockIdx.x * 256 + threadIdx.x;
    if (t >= total) return;
    int c = t & 63;
    float a  = pa[0];
    float m  = sums[c] * invN;
    float ms = gms[c];
    float var = sums[OUT_C + c] * invN - ms * m * m * (2.f - ms);
    float A = gw[c] * rsqrtf(var + GN_EPS);
    float v = out[t];
    float y = v >= 0.f ? v : a * v;
    out[t] = A * (y - ms * m) + gb[c];
}

// ---------------------------------------------------------------------------
extern "C" void kernel_launch(void* const* d_in, const int* in_sizes, int n_in,
                              void* d_out, int out_size, void* d_ws, size_t ws_size,
                              hipStream_t stream) {
    (void)n_in; (void)out_size;
    const float* x    = (const float*)d_in[0];
    const int*   ei   = (const int*)  d_in[1];   // [2,E] row-major int32
    const float* ea   = (const float*)d_in[2];
    const float* lw   = (const float*)d_in[3];
    const float* bias = (const float*)d_in[4];
    const float* w1   = (const float*)d_in[5];
    const float* b1   = (const float*)d_in[6];
    const float* w2   = (const float*)d_in[7];
    const float* b2   = (const float*)d_in[8];
    const float* pa   = (const float*)d_in[9];
    const float* gw   = (const float*)d_in[10];
    const float* gb   = (const float*)d_in[11];
    const float* gms  = (const float*)d_in[12];
    float* out = (float*)d_out;

    int N = in_sizes[0] / IN_C;
    int E = in_sizes[2] / EDIM;
    int total = N * OUT_C;
    int nbN = (N + 255) / 256;
    int nbE = (E + 255) / 256;

    // workspace layout (degcnt first for 8B alignment; rec LAST for fallback)
    char* p = (char*)d_ws;
    u64*   degcnt = (u64*)p;  p += sizeof(u64) * (size_t)N;
    float* dinv   = (float*)p; p += sizeof(float) * (size_t)N;
    float* xts    = (float*)p; p += sizeof(float) * (size_t)N * OUT_C;
    float* sums   = (float*)p; p += sizeof(float) * 128;
    int*   cnt    = (int*)p;   p += sizeof(int) * (size_t)N;
    int*   startv = (int*)p;   p += sizeof(int) * (size_t)N;
    int*   bsums  = (int*)p;   p += sizeof(int) * 1024;
    int2*  tmp    = (int2*)p;  p += sizeof(int2) * (size_t)E;
    int2*  rec    = (int2*)p;  p += sizeof(int2) * (size_t)E;
    size_t need = (size_t)(p - (char*)d_ws);
    bool use_csr = (need <= ws_size) && (nbN <= 1024);

    k_init <<<nbN, 256, 0, stream>>>(degcnt, sums, N);
    k_edge <<<nbE, 256, 0, stream>>>(ea, ei, w1, b1, w2, b2, degcnt, tmp, E);

    if (use_csr) {
        k_scan1 <<<nbN, 256, 0, stream>>>(degcnt, startv, bsums, dinv, cnt, N);
        k_scan2 <<<1, 1024, 0, stream>>>(bsums, nbN);
        k_pass2 <<<nbE, 256, 0, stream>>>(ei, tmp, startv, bsums, rec, E);
        k_xt    <<<(N + 63) / 64, 256, 0, stream>>>(x, lw, dinv, xts, N);
        k_gather<<<(N + 3) / 4, 256, 0, stream>>>(rec, startv, bsums, cnt, dinv, xts, bias, out, N);
    } else {
        k_finish<<<nbN, 256, 0, stream>>>(degcnt, dinv, cnt, N);
        k_xt    <<<(N + 63) / 64, 256, 0, stream>>>(x, lw, dinv, xts, N);
        k_init_out<<<(total + 255) / 256, 256, 0, stream>>>(bias, dinv, xts, out, total);
        long st = (long)E * 64;
        k_scatter <<<(unsigned)((st + 255) / 256), 256, 0, stream>>>(ei, tmp, dinv, xts, out, E);
    }

    k_stats <<<512, 256, 0, stream>>>(out, pa, sums, total);
    k_apply <<<(total + 255) / 256, 256, 0, stream>>>(out, pa, sums, gw, gb, gms, total,
                                                      1.0f / (float)N);
}

// Round 5
// 464.395 us; speedup vs baseline: 1.1283x; 1.1283x over previous
//
#include <hip/hip_runtime.h>
#include <math.h>

#define IN_C   128
#define OUT_C  64
#define EDIM   16
#define EHID   32
#define GN_EPS 1e-5f

typedef unsigned long long u64;

__device__ __forceinline__ float dot4(float4 a, float4 b) {
    return a.x * b.x + a.y * b.y + a.z * b.z + a.w * b.w;
}
__device__ __forceinline__ void fma4(float4& a, float s, float4 w) {
    a.x = fmaf(s, w.x, a.x); a.y = fmaf(s, w.y, a.y);
    a.z = fmaf(s, w.z, a.z); a.w = fmaf(s, w.w, a.w);
}
__device__ __forceinline__ float getc(float4 v, int j) {
    return j == 0 ? v.x : j == 1 ? v.y : j == 2 ? v.z : v.w;
}

// ---------------------------------------------------------------------------
// K0: init  degcnt = {cnt:0, deg:1.0 fixed-point} (self-loop), sums = 0
// ---------------------------------------------------------------------------
__global__ void k_init(u64* __restrict__ degcnt, float* __restrict__ sums, int N) {
    int i = blockIdx.x * 256 + threadIdx.x;
    if (i < N) degcnt[i] = (1ull << 32);          // deg = 1.0 in 2^32 fixed point
    if (i < 2 * OUT_C) sums[i] = 0.f;
}

// ---------------------------------------------------------------------------
// K1: fused edge phase — SCALAR-PIPE weights. R0's k_edge was LDS-issue-bound
// (128 ds_read_b128/wave ≈ 62us CU LDS-pipe occupancy; VALUBusy only 28%).
// R4's split-K broke the wave-uniform broadcast (6.4M bank conflicts). This
// version removes LDS entirely: weight reads use wave-UNIFORM global
// addresses with compile-time indices -> compiler scalarizes to s_load via
// the scalar/constant cache (2KB, resident). ~32 scalar loads/wave replace
// 128 LDS instrs; VALU work unchanged.
// ATOMIC SCHEME UNCHANGED (R0-proven): ONE u64 RMW-with-return per thread,
// issued AFTER the MLP. R1 (early issue) and R2 (4 atomics/thread) both
// triggered a ~20x cross-XCD coherence storm — do not deviate.
// tmp[e] = {row | rank<<17, ew}
// ---------------------------------------------------------------------------
__global__ void k_edge(const float* __restrict__ ea, const int* __restrict__ ei,
                       const float* __restrict__ w1, const float* __restrict__ b1,
                       const float* __restrict__ w2, const float* __restrict__ b2,
                       u64* __restrict__ degcnt, int2* __restrict__ tmp, int E) {
    int e = blockIdx.x * 256 + threadIdx.x;
    if (e >= E) return;

    const float4* eav = (const float4*)ea + (size_t)e * 4;
    float4 a0 = eav[0], a1 = eav[1], a2 = eav[2], a3 = eav[3];

    const float4* w1v = (const float4*)w1;    // row j = w1v[j*4 .. j*4+3], uniform
    float z = b2[0];
    #pragma unroll
    for (int j = 0; j < EHID; ++j) {
        float4 q0 = w1v[j * 4 + 0];
        float4 q1 = w1v[j * 4 + 1];
        float4 q2 = w1v[j * 4 + 2];
        float4 q3 = w1v[j * 4 + 3];
        float h = dot4(a0, q0) + dot4(a1, q1) + dot4(a2, q2) + dot4(a3, q3) + b1[j];
        h = fmaxf(h, 0.f);
        z += h * w2[j];
    }
    float ewv = 1.f / (1.f + __expf(-z));

    int row = ei[e];
    int col = ei[E + e];
    u64 inc = (1ull << 44) | (u64)(ewv * 4294967296.0f);   // {cnt+=1, deg+=ew}
    u64 old = atomicAdd(&degcnt[col], inc);
    int rank = (int)(old >> 44);                            // edges before this one
    tmp[e] = make_int2(row | (rank << 17), __float_as_int(ewv));
}

// ---------------------------------------------------------------------------
// K2 (fallback path only): unpack degcnt -> dinv and cnt
// ---------------------------------------------------------------------------
__global__ void k_finish(const u64* __restrict__ degcnt, float* __restrict__ dinv,
                         int* __restrict__ cnt, int N) {
    int i = blockIdx.x * 256 + threadIdx.x;
    if (i < N) {
        u64 v = degcnt[i];
        float deg = (float)(v & ((1ull << 44) - 1)) * (1.f / 4294967296.f);
        dinv[i] = rsqrtf(deg);                    // deg >= 1 always
        cnt[i] = (int)(v >> 44);
    }
}

// ---------------------------------------------------------------------------
// scan1 (CSR path): fused k_finish + block-local exclusive scan of cnt.
// full_start(i) = start[i] + bsums[i>>8]  (scan3 fused into consumers)
// ---------------------------------------------------------------------------
__global__ void k_scan1(const u64* __restrict__ degcnt, int* __restrict__ start,
                        int* __restrict__ bsums, float* __restrict__ dinv,
                        int* __restrict__ cnt, int N) {
    __shared__ int s[256];
    int t = threadIdx.x;
    int i = blockIdx.x * 256 + t;
    int v = 0;
    if (i < N) {
        u64 dv = degcnt[i];
        v = (int)(dv >> 44);
        float deg = (float)(dv & ((1ull << 44) - 1)) * (1.f / 4294967296.f);
        dinv[i] = rsqrtf(deg);
        cnt[i] = v;
    }
    s[t] = v;
    __syncthreads();
    #pragma unroll
    for (int off = 1; off < 256; off <<= 1) {
        int u = (t >= off) ? s[t - off] : 0;
        __syncthreads();
        s[t] += u;
        __syncthreads();
    }
    if (i < N) start[i] = s[t] - v;
    if (t == 255) bsums[blockIdx.x] = s[255];
}
__global__ void k_scan2(int* __restrict__ bsums, int nb) {
    __shared__ int s[1024];
    int t = threadIdx.x;
    s[t] = (t < nb) ? bsums[t] : 0;
    __syncthreads();
    #pragma unroll
    for (int off = 1; off < 1024; off <<= 1) {
        int u = (t >= off) ? s[t - off] : 0;
        __syncthreads();
        s[t] += u;
        __syncthreads();
    }
    if (t < nb) bsums[t] = (t == 0) ? 0 : s[t - 1];
}

// ---------------------------------------------------------------------------
// pass2: atomic-free permute — rec[full_start[col]+rank] = {row, ew}
// ---------------------------------------------------------------------------
__global__ void k_pass2(const int* __restrict__ ei, const int2* __restrict__ tmp,
                        const int* __restrict__ start, const int* __restrict__ bsums,
                        int2* __restrict__ rec, int E) {
    int e = blockIdx.x * 256 + threadIdx.x;
    if (e >= E) return;
    int col = ei[E + e];
    int2 t = tmp[e];
    int rank = ((unsigned)t.x) >> 17;
    int pos = start[col] + bsums[col >> 8] + rank;
    rec[pos] = make_int2(t.x & 0x1FFFF, t.y);
}

// ---------------------------------------------------------------------------
// K3: xts = dinv * (x @ lin_w^T)  — register-tiled 4 rows x 4 ch/lane
// ---------------------------------------------------------------------------
__global__ void k_xt(const float* __restrict__ x, const float* __restrict__ lw,
                     const float* __restrict__ dinv, float* __restrict__ xts, int N) {
    __shared__ float swt[IN_C * OUT_C];
    int tid = threadIdx.x;
    for (int i = tid; i < IN_C * OUT_C; i += 256) {
        int k = i >> 6, c = i & 63;
        swt[i] = lw[c * IN_C + k];
    }
    __syncthreads();

    int lane = tid & 63;
    int c4 = lane & 15;
    int rq = lane >> 4;
    int rbase = blockIdx.x * 64 + (tid >> 6) * 16 + rq * 4;

    int r0 = min(rbase + 0, N - 1), r1 = min(rbase + 1, N - 1);
    int r2 = min(rbase + 2, N - 1), r3 = min(rbase + 3, N - 1);
    const float4* x4 = (const float4*)x;
    float4 acc0 = {0,0,0,0}, acc1 = {0,0,0,0}, acc2 = {0,0,0,0}, acc3 = {0,0,0,0};

    #pragma unroll 4
    for (int k4 = 0; k4 < IN_C / 4; ++k4) {
        float4 xv0 = x4[(size_t)r0 * 32 + k4];
        float4 xv1 = x4[(size_t)r1 * 32 + k4];
        float4 xv2 = x4[(size_t)r2 * 32 + k4];
        float4 xv3 = x4[(size_t)r3 * 32 + k4];
        #pragma unroll
        for (int j = 0; j < 4; ++j) {
            float4 wv = *(const float4*)&swt[(k4 * 4 + j) * OUT_C + (c4 << 2)];
            fma4(acc0, getc(xv0, j), wv);
            fma4(acc1, getc(xv1, j), wv);
            fma4(acc2, getc(xv2, j), wv);
            fma4(acc3, getc(xv3, j), wv);
        }
    }
    int cc = c4 << 2;
    #pragma unroll
    for (int i = 0; i < 4; ++i) {
        int r = rbase + i;
        if (r < N) {
            float d = dinv[r];
            float4 a = i == 0 ? acc0 : i == 1 ? acc1 : i == 2 ? acc2 : acc3;
            a.x *= d; a.y *= d; a.z *= d; a.w *= d;
            *(float4*)&xts[(size_t)r * OUT_C + cc] = a;
        }
    }
}

// ---------------------------------------------------------------------------
// gather: one wave per node, lane = channel; unroll-8.
// out = bias + dinv[node] * (sum_j ew_j * xts[row_j] + xts[node])
// ---------------------------------------------------------------------------
__global__ void k_gather(const int2* __restrict__ rec, const int* __restrict__ start,
                         const int* __restrict__ bsums, const int* __restrict__ cnt,
                         const float* __restrict__ dinv, const float* __restrict__ xts,
                         const float* __restrict__ bias, float* __restrict__ out, int N) {
    int node = blockIdx.x * 4 + (threadIdx.x >> 6);
    if (node >= N) return;
    int lane = threadIdx.x & 63;
    int beg = start[node] + bsums[node >> 8];
    int num = cnt[node];
    float acc = xts[((size_t)node << 6) + lane];      // self-loop term
    int j = 0;
    for (; j + 8 <= num; j += 8) {
        int2 rc[8];
        #pragma unroll
        for (int u = 0; u < 8; ++u) rc[u] = rec[beg + j + u];
        float v[8];
        #pragma unroll
        for (int u = 0; u < 8; ++u) v[u] = xts[((size_t)rc[u].x << 6) + lane];
        #pragma unroll
        for (int u = 0; u < 8; ++u) acc = fmaf(__int_as_float(rc[u].y), v[u], acc);
    }
    for (; j < num; ++j) {
        int2 rc = rec[beg + j];
        acc = fmaf(__int_as_float(rc.y), xts[((size_t)rc.x << 6) + lane], acc);
    }
    out[((size_t)node << 6) + lane] = bias[lane] + dinv[node] * acc;
}

// ---------------------------------------------------------------------------
// fallback (emergency, if ws too small for rec): atomic scatter path
// ---------------------------------------------------------------------------
__global__ void k_init_out(const float* __restrict__ bias, const float* __restrict__ dinv,
                           const float* __restrict__ xts, float* __restrict__ out, int total) {
    int t = blockIdx.x * 256 + threadIdx.x;
    if (t >= total) return;
    int i = t >> 6, c = t & 63;
    out[t] = bias[c] + dinv[i] * xts[t];
}
__global__ void k_scatter(const int* __restrict__ ei, const int2* __restrict__ tmp,
                          const float* __restrict__ dinv, const float* __restrict__ xts,
                          float* __restrict__ out, int E) {
    int t = blockIdx.x * 256 + threadIdx.x;
    int e = t >> 6;
    if (e >= E) return;
    int lane = t & 63;
    int2 tm = tmp[e];
    int row = tm.x & 0x1FFFF;
    int col = ei[E + e];
    float w = dinv[col] * __int_as_float(tm.y);
    atomicAdd(out + (size_t)col * OUT_C + lane, w * xts[(size_t)row * OUT_C + lane]);
}

// ---------------------------------------------------------------------------
// PReLU + GraphNorm stats + apply
// ---------------------------------------------------------------------------
__global__ void k_stats(const float* __restrict__ out, const float* __restrict__ pa,
                        float* __restrict__ sums, int total) {
    __shared__ float r1[256], r2[256];
    float a = pa[0];
    float s = 0.f, s2 = 0.f;
    int stride = gridDim.x * 256;
    for (int t = blockIdx.x * 256 + threadIdx.x; t < total; t += stride) {
        float v = out[t];
        float y = v >= 0.f ? v : a * v;
        s += y; s2 += y * y;
    }
    int tid = threadIdx.x;
    r1[tid] = s; r2[tid] = s2;
    __syncthreads();
    if (tid < 64) {
        float t1 = r1[tid] + r1[tid + 64] + r1[tid + 128] + r1[tid + 192];
        float t2 = r2[tid] + r2[tid + 64] + r2[tid + 128] + r2[tid + 192];
        atomicAdd(&sums[tid], t1);
        atomicAdd(&sums[OUT_C + tid], t2);
    }
}
__global__ void k_apply(float* __restrict__ out, const float* __restrict__ pa,
                        const float* __restrict__ sums,
                        const float* __restrict__ gw, const float* __restrict__ gb,
                        const float* __restrict__ gms, int total, float invN) {
    int t = blockIdx.x * 256 + threadIdx.x;
    if (t >= total) return;
    int c = t & 63;
    float a  = pa[0];
    float m  = sums[c] * invN;
    float ms = gms[c];
    float var = sums[OUT_C + c] * invN - ms * m * m * (2.f - ms);
    float A = gw[c] * rsqrtf(var + GN_EPS);
    float v = out[t];
    float y = v >= 0.f ? v : a * v;
    out[t] = A * (y - ms * m) + gb[c];
}

// ---------------------------------------------------------------------------
extern "C" void kernel_launch(void* const* d_in, const int* in_sizes, int n_in,
                              void* d_out, int out_size, void* d_ws, size_t ws_size,
                              hipStream_t stream) {
    (void)n_in; (void)out_size;
    const float* x    = (const float*)d_in[0];
    const int*   ei   = (const int*)  d_in[1];   // [2,E] row-major int32
    const float* ea   = (const float*)d_in[2];
    const float* lw   = (const float*)d_in[3];
    const float* bias = (const float*)d_in[4];
    const float* w1   = (const float*)d_in[5];
    const float* b1   = (const float*)d_in[6];
    const float* w2   = (const float*)d_in[7];
    const float* b2   = (const float*)d_in[8];
    const float* pa   = (const float*)d_in[9];
    const float* gw   = (const float*)d_in[10];
    const float* gb   = (const float*)d_in[11];
    const float* gms  = (const float*)d_in[12];
    float* out = (float*)d_out;

    int N = in_sizes[0] / IN_C;
    int E = in_sizes[2] / EDIM;
    int total = N * OUT_C;
    int nbN = (N + 255) / 256;
    int nbE = (E + 255) / 256;

    // workspace layout (degcnt first for 8B alignment; rec LAST for fallback)
    char* p = (char*)d_ws;
    u64*   degcnt = (u64*)p;  p += sizeof(u64) * (size_t)N;
    float* dinv   = (float*)p; p += sizeof(float) * (size_t)N;
    float* xts    = (float*)p; p += sizeof(float) * (size_t)N * OUT_C;
    float* sums   = (float*)p; p += sizeof(float) * 128;
    int*   cnt    = (int*)p;   p += sizeof(int) * (size_t)N;
    int*   startv = (int*)p;   p += sizeof(int) * (size_t)N;
    int*   bsums  = (int*)p;   p += sizeof(int) * 1024;
    int2*  tmp    = (int2*)p;  p += sizeof(int2) * (size_t)E;
    int2*  rec    = (int2*)p;  p += sizeof(int2) * (size_t)E;
    size_t need = (size_t)(p - (char*)d_ws);
    bool use_csr = (need <= ws_size) && (nbN <= 1024);

    k_init <<<nbN, 256, 0, stream>>>(degcnt, sums, N);
    k_edge <<<nbE, 256, 0, stream>>>(ea, ei, w1, b1, w2, b2, degcnt, tmp, E);

    if (use_csr) {
        k_scan1 <<<nbN, 256, 0, stream>>>(degcnt, startv, bsums, dinv, cnt, N);
        k_scan2 <<<1, 1024, 0, stream>>>(bsums, nbN);
        k_pass2 <<<nbE, 256, 0, stream>>>(ei, tmp, startv, bsums, rec, E);
        k_xt    <<<(N + 63) / 64, 256, 0, stream>>>(x, lw, dinv, xts, N);
        k_gather<<<(N + 3) / 4, 256, 0, stream>>>(rec, startv, bsums, cnt, dinv, xts, bias, out, N);
    } else {
        k_finish<<<nbN, 256, 0, stream>>>(degcnt, dinv, cnt, N);
        k_xt    <<<(N + 63) / 64, 256, 0, stream>>>(x, lw, dinv, xts, N);
        k_init_out<<<(total + 255) / 256, 256, 0, stream>>>(bias, dinv, xts, out, total);
        long st = (long)E * 64;
        k_scatter <<<(unsigned)((st + 255) / 256), 256, 0, stream>>>(ei, tmp, dinv, xts, out, E);
    }

    k_stats <<<512, 256, 0, stream>>>(out, pa, sums, total);
    k_apply <<<(total + 255) / 256, 256, 0, stream>>>(out, pa, sums, gw, gb, gms, total,
                                                      1.0f / (float)N);
}